// Round 14
// baseline (298.958 us; speedup 1.0000x reference)
//
#include <hip/hip_runtime.h>
#include <hip/hip_bf16.h>

#define EPSV 1e-5f
#define BM   32
#define XSTR 552   // full-x row stride (bf16): 1104 B, 16B-aligned; holds 544 cols
#define DSTR 276   // delta row stride (f32) == XSTR/2

using bf16x8 = __attribute__((ext_vector_type(8))) short;
using f32x4  = __attribute__((ext_vector_type(4))) float;
using us4    = __attribute__((ext_vector_type(4))) unsigned short;
using us8    = __attribute__((ext_vector_type(8))) unsigned short;

// Manual RNE f32->bf16 (verified R1-R13; __float2bfloat16 header cast FAILED
// accuracy in R8; inline-asm v_cvt_pk_bf16_f32 was accurate but inflated
// liveness/spill and was net slower in R11/R13). Use this everywhere.
__device__ __forceinline__ unsigned short f2bf(float f) {
    unsigned int u = __float_as_uint(f);
    u += 0x7fffu + ((u >> 16) & 1u);   // RNE
    return (unsigned short)(u >> 16);
}

// packed-k -> original W0 row.  Packed: [logits 0..15 | hidden ..143 | msg ..287 | layer_pe ..415 | intra ..543]
// Original concat: logits(0..15) hidden(..143) layer_pe(..271) intra(..399) loss(400) msg(401..544)
__device__ __forceinline__ int orig_row(int k) {
    return (k < 144) ? k : ((k < 288) ? (k + 257) : (k - 144));
}
__device__ __forceinline__ float seg_pick(int k,
    const float* a, const float* b, const float* c, const float* d, const float* e) {
    if (k < 16)  return a[k];
    if (k < 144) return b[k - 16];
    if (k < 288) return c[k - 144];
    if (k < 416) return d[k - 288];
    return e[k - 416];
}

// ---------------- weight prep ----------------
// W0p holds s_cat[k] * W0[orig(k), n] in MFMA fragment order:
//   ((s*16 + t)*64 + lane)*8 + i  ->  k = 32*s + 8*(lane>>4) + i, n = 16*t + (lane&15)
// b0e[n] = b0[n] + ln_loss_b*W0[400,n] + sum_k b_cat[k]*W0[orig(k),n]  (k-parallel)
__global__ void prep_kernel(const float* __restrict__ W0, const float* __restrict__ b0,
                            const float* __restrict__ ln_loss_b,
                            const float* __restrict__ W1, const float* __restrict__ W2,
                            const float* __restrict__ ls_s, const float* __restrict__ hs_s,
                            const float* __restrict__ ms_s, const float* __restrict__ pe_s,
                            const float* __restrict__ in_s,
                            const float* __restrict__ ls_b, const float* __restrict__ hs_b,
                            const float* __restrict__ ms_b, const float* __restrict__ pe_b,
                            const float* __restrict__ in_b,
                            unsigned short* __restrict__ W0p, unsigned short* __restrict__ W1p,
                            unsigned short* __restrict__ W2p, float* __restrict__ b0e)
{
    int gtid = blockIdx.x * blockDim.x + threadIdx.x;
    if (gtid < 17408) {                       // W0p: 17 ksteps x 16 ntiles (scaled)
        int lane = gtid & 63, fid = gtid >> 6;
        int s = fid >> 4, t = fid & 15;
        int n  = (t << 4) + (lane & 15);
        int kb = (s << 5) + ((lane >> 4) << 3);
        us8 v;
        #pragma unroll
        for (int i = 0; i < 8; ++i) {
            int k = kb + i;
            float sc = seg_pick(k, ls_s, hs_s, ms_s, pe_s, in_s);
            v[i] = f2bf(sc * W0[orig_row(k) * 256 + n]);
        }
        *reinterpret_cast<us8*>(W0p + gtid * 8) = v;
    } else if (gtid < 17408 + 8192) {         // W1p: 8 x 16
        int g = gtid - 17408;
        int lane = g & 63, fid = g >> 6;
        int s = fid >> 4, t = fid & 15;
        int n  = (t << 4) + (lane & 15);
        int kb = (s << 5) + ((lane >> 4) << 3);
        us8 v;
        #pragma unroll
        for (int i = 0; i < 8; ++i) v[i] = f2bf(W1[(kb + i) * 256 + n]);
        *reinterpret_cast<us8*>(W1p + g * 8) = v;
    } else if (gtid < 17408 + 8192 + 4608) {  // W2p: 8 x 9
        int g = gtid - 17408 - 8192;
        int lane = g & 63, fid = g >> 6;
        int s = fid / 9, t = fid % 9;
        int n  = (t << 4) + (lane & 15);
        int kb = (s << 5) + ((lane >> 4) << 3);
        us8 v;
        #pragma unroll
        for (int i = 0; i < 8; ++i) v[i] = f2bf(W2[(kb + i) * 144 + n]);
        *reinterpret_cast<us8*>(W2p + g * 8) = v;
    } else if (gtid < 17408 + 8192 + 4608 + 8192) {
        // b0e: k-parallel fold. idx = (n<<5)|sub ; thread sums k = sub + 32*j.
        int idx = gtid - (17408 + 8192 + 4608);
        int n   = idx >> 5;
        int sub = idx & 31;
        float acc = 0.f;
        #pragma unroll
        for (int j = 0; j < 17; ++j) {
            int k = sub + 32 * j;
            float bb = seg_pick(k, ls_b, hs_b, ms_b, pe_b, in_b);
            acc += bb * W0[orig_row(k) * 256 + n];
        }
        acc += __shfl_xor(acc, 1);  acc += __shfl_xor(acc, 2);
        acc += __shfl_xor(acc, 4);  acc += __shfl_xor(acc, 8);
        acc += __shfl_xor(acc, 16);
        if (sub == 0)
            b0e[n] = acc + b0[n] + ln_loss_b[0] * W0[400 * 256 + n];
    }
}

// ---------------- input LN staging: 8 threads per row, 32 rows ----------------
// Stores (x - mu) * rstd  (scale/bias folded into W0p/b0e).  f2bf RNE packs.
template<int L>
__device__ __forceinline__ void stage8(
    const float* __restrict__ src,
    unsigned short* xb, int dstcol, int tid, int row0)
{
    constexpr int SPAN = L / 8;
    const int sub = tid & 7;
    const int r   = tid >> 3;                  // 0..31
    const float* p = src + (size_t)(row0 + r) * L + sub * SPAN;
    float ps = 0.f, pq = 0.f;
    if constexpr (SPAN % 4 == 0) {
        constexpr int NV = SPAN / 4;
        float4 v[NV];
        #pragma unroll
        for (int j = 0; j < NV; ++j) {
            v[j] = *reinterpret_cast<const float4*>(p + 4 * j);
            ps += v[j].x + v[j].y + v[j].z + v[j].w;
            pq += v[j].x * v[j].x + v[j].y * v[j].y + v[j].z * v[j].z + v[j].w * v[j].w;
        }
        ps += __shfl_xor(ps, 1); ps += __shfl_xor(ps, 2); ps += __shfl_xor(ps, 4);
        pq += __shfl_xor(pq, 1); pq += __shfl_xor(pq, 2); pq += __shfl_xor(pq, 4);
        const float mu   = ps * (1.f / L);
        const float rstd = rsqrtf(pq * (1.f / L) - mu * mu + EPSV);
        unsigned short* dst = xb + r * XSTR + dstcol + sub * SPAN;
        #pragma unroll
        for (int j = 0; j < NV; ++j) {
            us4 o;
            o[0] = f2bf((v[j].x - mu) * rstd);
            o[1] = f2bf((v[j].y - mu) * rstd);
            o[2] = f2bf((v[j].z - mu) * rstd);
            o[3] = f2bf((v[j].w - mu) * rstd);
            *reinterpret_cast<us4*>(dst + 4 * j) = o;
        }
    } else {
        constexpr int NV = SPAN / 2;
        float2 v[NV];
        #pragma unroll
        for (int j = 0; j < NV; ++j) {
            v[j] = *reinterpret_cast<const float2*>(p + 2 * j);
            ps += v[j].x + v[j].y;
            pq += v[j].x * v[j].x + v[j].y * v[j].y;
        }
        ps += __shfl_xor(ps, 1); ps += __shfl_xor(ps, 2); ps += __shfl_xor(ps, 4);
        pq += __shfl_xor(pq, 1); pq += __shfl_xor(pq, 2); pq += __shfl_xor(pq, 4);
        const float mu   = ps * (1.f / L);
        const float rstd = rsqrtf(pq * (1.f / L) - mu * mu + EPSV);
        unsigned short* dst = xb + r * XSTR + dstcol + sub * SPAN;
        #pragma unroll
        for (int j = 0; j < NV; ++j) {
            unsigned int pk = (unsigned int)f2bf((v[j].x - mu) * rstd)
                            | ((unsigned int)f2bf((v[j].y - mu) * rstd) << 16);
            *reinterpret_cast<unsigned int*>(dst + 2 * j) = pk;
        }
    }
}

// ---------------- fused main kernel ----------------
// BM=32, 4 waves. R14 = R10 (measured best, 287us) + sched_barrier(0) fences
// between stage segments: stops the compiler from merging the 5 segments'
// load batches (the liveness inflation behind R10's residual 50MB spill).
// Staging is f2bf (R11/R13 A/B: inline-asm cvt_pk inflates spill, net slower).
// No setprio (hurts barrier-synced GEMM). No unroll-2 / epilogue prefetch
// (R12: both regressed).
// LDS lifecycle: x full (544) -> h0 (256, overwrites) -> h1 -> delta f32 (144)
__global__ __launch_bounds__(256, 4) void node_update_kernel(
    const float* __restrict__ logits, const float* __restrict__ hidden,
    const float* __restrict__ layer_pe, const float* __restrict__ intra,
    const int* __restrict__ layer, const float* __restrict__ msg,
    const unsigned short* __restrict__ W0p, const float* __restrict__ b0e,
    const float* __restrict__ mlp_ln0_s, const float* __restrict__ mlp_ln0_b,
    const unsigned short* __restrict__ W1p, const float* __restrict__ b1,
    const float* __restrict__ mlp_ln1_s, const float* __restrict__ mlp_ln1_b,
    const unsigned short* __restrict__ W2p, const float* __restrict__ b2,
    float* __restrict__ out)
{
    __shared__ __align__(16) unsigned short sbuf[BM * XSTR];  // 35328 B, multi-purpose
    __shared__ __align__(16) float redf[BM * 4 * 2];          // 1024 B: [row][wave]{ps,pq}
    __shared__ int lyr[BM];

    float2* redp = reinterpret_cast<float2*>(redf);
    const float4* redq = reinterpret_cast<const float4*>(redf);
    const int tid  = threadIdx.x;
    const int lane = tid & 63;
    const int w    = tid >> 6;
    const int l15  = lane & 15;
    const int lg   = lane >> 4;
    const int row0 = blockIdx.x * BM;

    // ---- phase A: stage ALL 544 cols (normalized only; no accumulator live) ----
    stage8<16 >(logits,   sbuf,   0, tid, row0);
    __builtin_amdgcn_sched_barrier(0);
    stage8<128>(hidden,   sbuf,  16, tid, row0);
    __builtin_amdgcn_sched_barrier(0);
    stage8<144>(msg,      sbuf, 144, tid, row0);
    __builtin_amdgcn_sched_barrier(0);
    stage8<128>(layer_pe, sbuf, 288, tid, row0);
    __builtin_amdgcn_sched_barrier(0);
    stage8<128>(intra,    sbuf, 416, tid, row0);
    __builtin_amdgcn_sched_barrier(0);
    if (tid < BM) lyr[tid] = layer[row0 + tid];
    __syncthreads();

    // ---- GEMM1 (K=544), wave w owns cols 64w..64w+63, rows 0..31 ----
    f32x4 acc[2][4];
    #pragma unroll
    for (int m = 0; m < 2; ++m)
        #pragma unroll
        for (int t = 0; t < 4; ++t)
            acc[m][t] = (f32x4){0.f, 0.f, 0.f, 0.f};

    for (int s = 0; s < 17; ++s) {
        bf16x8 a[2];
        #pragma unroll
        for (int m = 0; m < 2; ++m)
            a[m] = *reinterpret_cast<const bf16x8*>(&sbuf[(16 * m + l15) * XSTR + 32 * s + 8 * lg]);
        #pragma unroll
        for (int t = 0; t < 4; ++t) {
            bf16x8 b = *reinterpret_cast<const bf16x8*>(W0p + (((s * 16 + w * 4 + t) * 64 + lane) << 3));
            #pragma unroll
            for (int m = 0; m < 2; ++m)
                acc[m][t] = __builtin_amdgcn_mfma_f32_16x16x32_bf16(a[m], b, acc[m][t], 0, 0, 0);
        }
    }

    // ---- LN0 + ReLU -> h0 (bf16, overwrites x in sbuf after barrier) ----
    {
        float bv[4], sv[4], bb[4];
        #pragma unroll
        for (int t = 0; t < 4; ++t) {
            int n = w * 64 + t * 16 + l15;
            bv[t] = b0e[n]; sv[t] = mlp_ln0_s[n]; bb[t] = mlp_ln0_b[n];
        }
        #pragma unroll
        for (int m = 0; m < 2; ++m)
            #pragma unroll
            for (int t = 0; t < 4; ++t)
                #pragma unroll
                for (int i = 0; i < 4; ++i)
                    acc[m][t][i] += bv[t];
        #pragma unroll
        for (int m = 0; m < 2; ++m) {
            #pragma unroll
            for (int i = 0; i < 4; ++i) {
                float ps = acc[m][0][i] + acc[m][1][i] + acc[m][2][i] + acc[m][3][i];
                float pq = acc[m][0][i] * acc[m][0][i] + acc[m][1][i] * acc[m][1][i]
                         + acc[m][2][i] * acc[m][2][i] + acc[m][3][i] * acc[m][3][i];
                ps += __shfl_xor(ps, 1); ps += __shfl_xor(ps, 2); ps += __shfl_xor(ps, 4); ps += __shfl_xor(ps, 8);
                pq += __shfl_xor(pq, 1); pq += __shfl_xor(pq, 2); pq += __shfl_xor(pq, 4); pq += __shfl_xor(pq, 8);
                if (l15 == 0) redp[(16 * m + 4 * lg + i) * 4 + w] = make_float2(ps, pq);
            }
        }
        __syncthreads();   // all GEMM1 LDS reads + partials done
        #pragma unroll
        for (int m = 0; m < 2; ++m)
            #pragma unroll
            for (int i = 0; i < 4; ++i) {
                int r = 16 * m + 4 * lg + i;
                float4 q0 = redq[r * 2 + 0], q1 = redq[r * 2 + 1];
                float s  = q0.x + q0.z + q1.x + q1.z;
                float q  = q0.y + q0.w + q1.y + q1.w;
                float mu = s * (1.f / 256.f);
                float rstd = rsqrtf(q * (1.f / 256.f) - mu * mu + EPSV);
                #pragma unroll
                for (int t = 0; t < 4; ++t) {
                    float y = (acc[m][t][i] - mu) * rstd * sv[t] + bb[t];
                    sbuf[r * XSTR + w * 64 + t * 16 + l15] = f2bf(fmaxf(y, 0.f));
                }
            }
    }
    __syncthreads();

    // ---- GEMM2 (256x256) reading h0 from sbuf ----
    #pragma unroll
    for (int m = 0; m < 2; ++m)
        #pragma unroll
        for (int t = 0; t < 4; ++t)
            acc[m][t] = (f32x4){0.f, 0.f, 0.f, 0.f};
    for (int s = 0; s < 8; ++s) {
        bf16x8 a[2];
        #pragma unroll
        for (int m = 0; m < 2; ++m)
            a[m] = *reinterpret_cast<const bf16x8*>(&sbuf[(16 * m + l15) * XSTR + 32 * s + 8 * lg]);
        #pragma unroll
        for (int t = 0; t < 4; ++t) {
            bf16x8 b = *reinterpret_cast<const bf16x8*>(W1p + (((s * 16 + w * 4 + t) * 64 + lane) << 3));
            #pragma unroll
            for (int m = 0; m < 2; ++m)
                acc[m][t] = __builtin_amdgcn_mfma_f32_16x16x32_bf16(a[m], b, acc[m][t], 0, 0, 0);
        }
    }

    // ---- LN1 + ReLU -> h1 (overwrites h0 in sbuf after barrier) ----
    {
        float bv[4], sv[4], bb[4];
        #pragma unroll
        for (int t = 0; t < 4; ++t) {
            int n = w * 64 + t * 16 + l15;
            bv[t] = b1[n]; sv[t] = mlp_ln1_s[n]; bb[t] = mlp_ln1_b[n];
        }
        #pragma unroll
        for (int m = 0; m < 2; ++m)
            #pragma unroll
            for (int t = 0; t < 4; ++t)
                #pragma unroll
                for (int i = 0; i < 4; ++i)
                    acc[m][t][i] += bv[t];
        #pragma unroll
        for (int m = 0; m < 2; ++m) {
            #pragma unroll
            for (int i = 0; i < 4; ++i) {
                float ps = acc[m][0][i] + acc[m][1][i] + acc[m][2][i] + acc[m][3][i];
                float pq = acc[m][0][i] * acc[m][0][i] + acc[m][1][i] * acc[m][1][i]
                         + acc[m][2][i] * acc[m][2][i] + acc[m][3][i] * acc[m][3][i];
                ps += __shfl_xor(ps, 1); ps += __shfl_xor(ps, 2); ps += __shfl_xor(ps, 4); ps += __shfl_xor(ps, 8);
                pq += __shfl_xor(pq, 1); pq += __shfl_xor(pq, 2); pq += __shfl_xor(pq, 4); pq += __shfl_xor(pq, 8);
                if (l15 == 0) redp[(16 * m + 4 * lg + i) * 4 + w] = make_float2(ps, pq);
            }
        }
        __syncthreads();   // all GEMM2 LDS reads + partials done
        #pragma unroll
        for (int m = 0; m < 2; ++m)
            #pragma unroll
            for (int i = 0; i < 4; ++i) {
                int r = 16 * m + 4 * lg + i;
                float4 q0 = redq[r * 2 + 0], q1 = redq[r * 2 + 1];
                float s  = q0.x + q0.z + q1.x + q1.z;
                float q  = q0.y + q0.w + q1.y + q1.w;
                float mu = s * (1.f / 256.f);
                float rstd = rsqrtf(q * (1.f / 256.f) - mu * mu + EPSV);
                #pragma unroll
                for (int t = 0; t < 4; ++t) {
                    float y = (acc[m][t][i] - mu) * rstd * sv[t] + bb[t];
                    sbuf[r * XSTR + w * 64 + t * 16 + l15] = f2bf(fmaxf(y, 0.f));
                }
            }
    }
    __syncthreads();

    // ---- GEMM3 (32x256 @ 256x144): wave w -> rows 16*(w&1).., col-half (w>>1) ----
    // Fully-static per-branch loops (rule #20)
    {
        const int rg = w & 1;
        const int ch = w >> 1;
        const unsigned short* arow = sbuf + (16 * rg + l15) * XSTR;
        float* delta = reinterpret_cast<float*>(sbuf);
        if (ch == 0) {
            f32x4 acc3[5];
            #pragma unroll
            for (int t = 0; t < 5; ++t) acc3[t] = (f32x4){0.f, 0.f, 0.f, 0.f};
            for (int s = 0; s < 8; ++s) {
                bf16x8 a = *reinterpret_cast<const bf16x8*>(arow + 32 * s + 8 * lg);
                #pragma unroll
                for (int t = 0; t < 5; ++t) {
                    bf16x8 b = *reinterpret_cast<const bf16x8*>(W2p + (((s * 9 + t) * 64 + lane) << 3));
                    acc3[t] = __builtin_amdgcn_mfma_f32_16x16x32_bf16(a, b, acc3[t], 0, 0, 0);
                }
            }
            __syncthreads();   // all h1 LDS reads done before delta overwrite
            #pragma unroll
            for (int t = 0; t < 5; ++t)
                #pragma unroll
                for (int i = 0; i < 4; ++i)
                    delta[(16 * rg + 4 * lg + i) * DSTR + 16 * t + l15] = acc3[t][i];
        } else {
            f32x4 acc3[4];
            #pragma unroll
            for (int t = 0; t < 4; ++t) acc3[t] = (f32x4){0.f, 0.f, 0.f, 0.f};
            for (int s = 0; s < 8; ++s) {
                bf16x8 a = *reinterpret_cast<const bf16x8*>(arow + 32 * s + 8 * lg);
                #pragma unroll
                for (int t = 0; t < 4; ++t) {
                    bf16x8 b = *reinterpret_cast<const bf16x8*>(W2p + (((s * 9 + t + 5) * 64 + lane) << 3));
                    acc3[t] = __builtin_amdgcn_mfma_f32_16x16x32_bf16(a, b, acc3[t], 0, 0, 0);
                }
            }
            __syncthreads();   // matches ch==0 barrier (uniform per block)
            #pragma unroll
            for (int t = 0; t < 4; ++t)
                #pragma unroll
                for (int i = 0; i < 4; ++i)
                    delta[(16 * rg + 4 * lg + i) * DSTR + 16 * (t + 5) + l15] = acc3[t][i];
        }
    }
    __syncthreads();

    // ---- epilogue: out = mask ? base + delta + b2 : base ----
    const float* delta = reinterpret_cast<const float*>(sbuf);
    #pragma unroll
    for (int j = 0; j < 5; ++j) {
        int idx = tid + j * 256;          // 0..1151 ; 36 float4 per row, 32 rows
        if (idx < BM * 36) {
            int r = idx / 36, c4 = idx % 36;
            int grow = row0 + r;
            float4 d  = *reinterpret_cast<const float4*>(delta + r * DSTR + 4 * c4);
            float4 bb = *reinterpret_cast<const float4*>(b2 + 4 * c4);
            float4 base;
            if (c4 < 4) base = *reinterpret_cast<const float4*>(logits + (size_t)grow * 16 + 4 * c4);
            else        base = *reinterpret_cast<const float4*>(hidden + (size_t)grow * 128 + 4 * c4 - 16);
            const bool mk = lyr[r] > 0;
            float4 o;
            o.x = mk ? base.x + d.x + bb.x : base.x;
            o.y = mk ? base.y + d.y + bb.y : base.y;
            o.z = mk ? base.z + d.z + bb.z : base.z;
            o.w = mk ? base.w + d.w + bb.w : base.w;
            *reinterpret_cast<float4*>(out + (size_t)grow * 144 + 4 * c4) = o;
        }
    }
}

extern "C" void kernel_launch(void* const* d_in, const int* in_sizes, int n_in,
                              void* d_out, int out_size, void* d_ws, size_t ws_size,
                              hipStream_t stream)
{
    const float* logits        = (const float*)d_in[0];
    const float* hidden        = (const float*)d_in[1];
    const float* layer_pe      = (const float*)d_in[2];
    const float* intra         = (const float*)d_in[3];
    // d_in[4] = loss: unused (LN of a scalar == its bias)
    const int*   layer         = (const int*)  d_in[5];
    const float* msg           = (const float*)d_in[6];
    const float* ln_logits_s   = (const float*)d_in[7];
    const float* ln_logits_b   = (const float*)d_in[8];
    const float* ln_hidden_s   = (const float*)d_in[9];
    const float* ln_hidden_b   = (const float*)d_in[10];
    const float* ln_layer_pe_s = (const float*)d_in[11];
    const float* ln_layer_pe_b = (const float*)d_in[12];
    const float* ln_intra_pe_s = (const float*)d_in[13];
    const float* ln_intra_pe_b = (const float*)d_in[14];
    // d_in[15] = ln_loss_s: unused
    const float* ln_loss_b     = (const float*)d_in[16];
    const float* ln_msg_s      = (const float*)d_in[17];
    const float* ln_msg_b      = (const float*)d_in[18];
    const float* W0            = (const float*)d_in[19];
    const float* b0            = (const float*)d_in[20];
    const float* mlp_ln0_s     = (const float*)d_in[21];
    const float* mlp_ln0_b     = (const float*)d_in[22];
    const float* W1            = (const float*)d_in[23];
    const float* b1            = (const float*)d_in[24];
    const float* mlp_ln1_s     = (const float*)d_in[25];
    const float* mlp_ln1_b     = (const float*)d_in[26];
    const float* W2            = (const float*)d_in[27];
    const float* b2            = (const float*)d_in[28];
    float* out = (float*)d_out;

    // workspace layout (485 KB): W0p | W1p | W2p | b0_eff
    unsigned short* W0p = (unsigned short*)d_ws;                     // 278528 B
    unsigned short* W1p = (unsigned short*)((char*)d_ws + 278528);   // 131072 B
    unsigned short* W2p = (unsigned short*)((char*)d_ws + 409600);   //  73728 B
    float*          b0e = (float*)((char*)d_ws + 483328);            //   1024 B

    // 17408 (W0p) + 8192 (W1p) + 4608 (W2p) + 8192 (b0e k-parallel) = 38400 = 150*256
    prep_kernel<<<150, 256, 0, stream>>>(W0, b0, ln_loss_b, W1, W2,
        ln_logits_s, ln_hidden_s, ln_msg_s, ln_layer_pe_s, ln_intra_pe_s,
        ln_logits_b, ln_hidden_b, ln_msg_b, ln_layer_pe_b, ln_intra_pe_b,
        W0p, W1p, W2p, b0e);

    const int N = in_sizes[5];               // 200000, divisible by BM=32
    node_update_kernel<<<N / BM, 256, 0, stream>>>(
        logits, hidden, layer_pe, intra, layer, msg,
        W0p, b0e, mlp_ln0_s, mlp_ln0_b,
        W1p, b1, mlp_ln1_s, mlp_ln1_b,
        W2p, b2, out);
}

// Round 16
// 279.221 us; speedup vs baseline: 1.0707x; 1.0707x over previous
//
#include <hip/hip_runtime.h>
#include <hip/hip_bf16.h>

#define EPSV 1e-5f
#define BM   32
#define XSTR 552   // full-x row stride (bf16): 1104 B, 16B-aligned; holds 544 cols
#define DSTR 276   // delta row stride (f32) == XSTR/2

using bf16x8 = __attribute__((ext_vector_type(8))) short;
using f32x4  = __attribute__((ext_vector_type(4))) float;
using us4    = __attribute__((ext_vector_type(4))) unsigned short;
using us8    = __attribute__((ext_vector_type(8))) unsigned short;

// Manual RNE f32->bf16 (verified R1-R14; __float2bfloat16 header cast FAILED
// accuracy in R8; inline-asm v_cvt_pk_bf16_f32 accurate but inflated
// liveness/spill, net slower R11/R13). Use this everywhere.
__device__ __forceinline__ unsigned short f2bf(float f) {
    unsigned int u = __float_as_uint(f);
    u += 0x7fffu + ((u >> 16) & 1u);   // RNE
    return (unsigned short)(u >> 16);
}

// packed-k -> original W0 row.  Packed: [logits 0..15 | hidden ..143 | msg ..287 | layer_pe ..415 | intra ..543]
// Original concat: logits(0..15) hidden(..143) layer_pe(..271) intra(..399) loss(400) msg(401..544)
__device__ __forceinline__ int orig_row(int k) {
    return (k < 144) ? k : ((k < 288) ? (k + 257) : (k - 144));
}
__device__ __forceinline__ float seg_pick(int k,
    const float* a, const float* b, const float* c, const float* d, const float* e) {
    if (k < 16)  return a[k];
    if (k < 144) return b[k - 16];
    if (k < 288) return c[k - 144];
    if (k < 416) return d[k - 288];
    return e[k - 416];
}

// ---------------- weight prep ----------------
// W0p holds s_cat[k] * W0[orig(k), n] in MFMA fragment order:
//   ((s*16 + t)*64 + lane)*8 + i  ->  k = 32*s + 8*(lane>>4) + i, n = 16*t + (lane&15)
// b0e[n] = b0[n] + ln_loss_b*W0[400,n] + sum_k b_cat[k]*W0[orig(k),n]  (k-parallel)
__global__ void prep_kernel(const float* __restrict__ W0, const float* __restrict__ b0,
                            const float* __restrict__ ln_loss_b,
                            const float* __restrict__ W1, const float* __restrict__ W2,
                            const float* __restrict__ ls_s, const float* __restrict__ hs_s,
                            const float* __restrict__ ms_s, const float* __restrict__ pe_s,
                            const float* __restrict__ in_s,
                            const float* __restrict__ ls_b, const float* __restrict__ hs_b,
                            const float* __restrict__ ms_b, const float* __restrict__ pe_b,
                            const float* __restrict__ in_b,
                            unsigned short* __restrict__ W0p, unsigned short* __restrict__ W1p,
                            unsigned short* __restrict__ W2p, float* __restrict__ b0e)
{
    int gtid = blockIdx.x * blockDim.x + threadIdx.x;
    if (gtid < 17408) {                       // W0p: 17 ksteps x 16 ntiles (scaled)
        int lane = gtid & 63, fid = gtid >> 6;
        int s = fid >> 4, t = fid & 15;
        int n  = (t << 4) + (lane & 15);
        int kb = (s << 5) + ((lane >> 4) << 3);
        us8 v;
        #pragma unroll
        for (int i = 0; i < 8; ++i) {
            int k = kb + i;
            float sc = seg_pick(k, ls_s, hs_s, ms_s, pe_s, in_s);
            v[i] = f2bf(sc * W0[orig_row(k) * 256 + n]);
        }
        *reinterpret_cast<us8*>(W0p + gtid * 8) = v;
    } else if (gtid < 17408 + 8192) {         // W1p: 8 x 16
        int g = gtid - 17408;
        int lane = g & 63, fid = g >> 6;
        int s = fid >> 4, t = fid & 15;
        int n  = (t << 4) + (lane & 15);
        int kb = (s << 5) + ((lane >> 4) << 3);
        us8 v;
        #pragma unroll
        for (int i = 0; i < 8; ++i) v[i] = f2bf(W1[(kb + i) * 256 + n]);
        *reinterpret_cast<us8*>(W1p + g * 8) = v;
    } else if (gtid < 17408 + 8192 + 4608) {  // W2p: 8 x 9
        int g = gtid - 17408 - 8192;
        int lane = g & 63, fid = g >> 6;
        int s = fid / 9, t = fid % 9;
        int n  = (t << 4) + (lane & 15);
        int kb = (s << 5) + ((lane >> 4) << 3);
        us8 v;
        #pragma unroll
        for (int i = 0; i < 8; ++i) v[i] = f2bf(W2[(kb + i) * 144 + n]);
        *reinterpret_cast<us8*>(W2p + g * 8) = v;
    } else if (gtid < 17408 + 8192 + 4608 + 8192) {
        // b0e: k-parallel fold. idx = (n<<5)|sub ; thread sums k = sub + 32*j.
        int idx = gtid - (17408 + 8192 + 4608);
        int n   = idx >> 5;
        int sub = idx & 31;
        float acc = 0.f;
        #pragma unroll
        for (int j = 0; j < 17; ++j) {
            int k = sub + 32 * j;
            float bb = seg_pick(k, ls_b, hs_b, ms_b, pe_b, in_b);
            acc += bb * W0[orig_row(k) * 256 + n];
        }
        acc += __shfl_xor(acc, 1);  acc += __shfl_xor(acc, 2);
        acc += __shfl_xor(acc, 4);  acc += __shfl_xor(acc, 8);
        acc += __shfl_xor(acc, 16);
        if (sub == 0)
            b0e[n] = acc + b0[n] + ln_loss_b[0] * W0[400 * 256 + n];
    }
}

// ---------------- input LN staging: 8 threads per row, 32 rows ----------------
// Stores (x - mu) * rstd  (scale/bias folded into W0p/b0e).  f2bf RNE packs.
template<int L>
__device__ __forceinline__ void stage8(
    const float* __restrict__ src,
    unsigned short* xb, int dstcol, int tid, int row0)
{
    constexpr int SPAN = L / 8;
    const int sub = tid & 7;
    const int r   = tid >> 3;                  // 0..31
    const float* p = src + (size_t)(row0 + r) * L + sub * SPAN;
    float ps = 0.f, pq = 0.f;
    if constexpr (SPAN % 4 == 0) {
        constexpr int NV = SPAN / 4;
        float4 v[NV];
        #pragma unroll
        for (int j = 0; j < NV; ++j) {
            v[j] = *reinterpret_cast<const float4*>(p + 4 * j);
            ps += v[j].x + v[j].y + v[j].z + v[j].w;
            pq += v[j].x * v[j].x + v[j].y * v[j].y + v[j].z * v[j].z + v[j].w * v[j].w;
        }
        ps += __shfl_xor(ps, 1); ps += __shfl_xor(ps, 2); ps += __shfl_xor(ps, 4);
        pq += __shfl_xor(pq, 1); pq += __shfl_xor(pq, 2); pq += __shfl_xor(pq, 4);
        const float mu   = ps * (1.f / L);
        const float rstd = rsqrtf(pq * (1.f / L) - mu * mu + EPSV);
        unsigned short* dst = xb + r * XSTR + dstcol + sub * SPAN;
        #pragma unroll
        for (int j = 0; j < NV; ++j) {
            us4 o;
            o[0] = f2bf((v[j].x - mu) * rstd);
            o[1] = f2bf((v[j].y - mu) * rstd);
            o[2] = f2bf((v[j].z - mu) * rstd);
            o[3] = f2bf((v[j].w - mu) * rstd);
            *reinterpret_cast<us4*>(dst + 4 * j) = o;
        }
    } else {
        constexpr int NV = SPAN / 2;
        float2 v[NV];
        #pragma unroll
        for (int j = 0; j < NV; ++j) {
            v[j] = *reinterpret_cast<const float2*>(p + 2 * j);
            ps += v[j].x + v[j].y;
            pq += v[j].x * v[j].x + v[j].y * v[j].y;
        }
        ps += __shfl_xor(ps, 1); ps += __shfl_xor(ps, 2); ps += __shfl_xor(ps, 4);
        pq += __shfl_xor(pq, 1); pq += __shfl_xor(pq, 2); pq += __shfl_xor(pq, 4);
        const float mu   = ps * (1.f / L);
        const float rstd = rsqrtf(pq * (1.f / L) - mu * mu + EPSV);
        unsigned short* dst = xb + r * XSTR + dstcol + sub * SPAN;
        #pragma unroll
        for (int j = 0; j < NV; ++j) {
            unsigned int pk = (unsigned int)f2bf((v[j].x - mu) * rstd)
                            | ((unsigned int)f2bf((v[j].y - mu) * rstd) << 16);
            *reinterpret_cast<unsigned int*>(dst + 2 * j) = pk;
        }
    }
}

// ---------------- fused main kernel ----------------
// R16 = exact R10 (measured best, 287us: f2bf staging, no fences, no setprio,
// no unroll pragmas, no epilogue prefetch) + non-temporal output stores via
// ext_vector f32x4 (R15's HIP float4 doesn't satisfy the builtin's type req).
// LDS lifecycle: x full (544) -> h0 (256, overwrites) -> h1 -> delta f32 (144)
__global__ __launch_bounds__(256, 4) void node_update_kernel(
    const float* __restrict__ logits, const float* __restrict__ hidden,
    const float* __restrict__ layer_pe, const float* __restrict__ intra,
    const int* __restrict__ layer, const float* __restrict__ msg,
    const unsigned short* __restrict__ W0p, const float* __restrict__ b0e,
    const float* __restrict__ mlp_ln0_s, const float* __restrict__ mlp_ln0_b,
    const unsigned short* __restrict__ W1p, const float* __restrict__ b1,
    const float* __restrict__ mlp_ln1_s, const float* __restrict__ mlp_ln1_b,
    const unsigned short* __restrict__ W2p, const float* __restrict__ b2,
    float* __restrict__ out)
{
    __shared__ __align__(16) unsigned short sbuf[BM * XSTR];  // 35328 B, multi-purpose
    __shared__ __align__(16) float redf[BM * 4 * 2];          // 1024 B: [row][wave]{ps,pq}
    __shared__ int lyr[BM];

    float2* redp = reinterpret_cast<float2*>(redf);
    const float4* redq = reinterpret_cast<const float4*>(redf);
    const int tid  = threadIdx.x;
    const int lane = tid & 63;
    const int w    = tid >> 6;
    const int l15  = lane & 15;
    const int lg   = lane >> 4;
    const int row0 = blockIdx.x * BM;

    // ---- phase A: stage ALL 544 cols (normalized only; no accumulator live) ----
    stage8<16 >(logits,   sbuf,   0, tid, row0);
    stage8<128>(hidden,   sbuf,  16, tid, row0);
    stage8<144>(msg,      sbuf, 144, tid, row0);
    stage8<128>(layer_pe, sbuf, 288, tid, row0);
    stage8<128>(intra,    sbuf, 416, tid, row0);
    if (tid < BM) lyr[tid] = layer[row0 + tid];
    __syncthreads();

    // ---- GEMM1 (K=544), wave w owns cols 64w..64w+63, rows 0..31 ----
    f32x4 acc[2][4];
    #pragma unroll
    for (int m = 0; m < 2; ++m)
        #pragma unroll
        for (int t = 0; t < 4; ++t)
            acc[m][t] = (f32x4){0.f, 0.f, 0.f, 0.f};

    for (int s = 0; s < 17; ++s) {
        bf16x8 a[2];
        #pragma unroll
        for (int m = 0; m < 2; ++m)
            a[m] = *reinterpret_cast<const bf16x8*>(&sbuf[(16 * m + l15) * XSTR + 32 * s + 8 * lg]);
        #pragma unroll
        for (int t = 0; t < 4; ++t) {
            bf16x8 b = *reinterpret_cast<const bf16x8*>(W0p + (((s * 16 + w * 4 + t) * 64 + lane) << 3));
            #pragma unroll
            for (int m = 0; m < 2; ++m)
                acc[m][t] = __builtin_amdgcn_mfma_f32_16x16x32_bf16(a[m], b, acc[m][t], 0, 0, 0);
        }
    }

    // ---- LN0 + ReLU -> h0 (bf16, overwrites x in sbuf after barrier) ----
    {
        float bv[4], sv[4], bb[4];
        #pragma unroll
        for (int t = 0; t < 4; ++t) {
            int n = w * 64 + t * 16 + l15;
            bv[t] = b0e[n]; sv[t] = mlp_ln0_s[n]; bb[t] = mlp_ln0_b[n];
        }
        #pragma unroll
        for (int m = 0; m < 2; ++m)
            #pragma unroll
            for (int t = 0; t < 4; ++t)
                #pragma unroll
                for (int i = 0; i < 4; ++i)
                    acc[m][t][i] += bv[t];
        #pragma unroll
        for (int m = 0; m < 2; ++m) {
            #pragma unroll
            for (int i = 0; i < 4; ++i) {
                float ps = acc[m][0][i] + acc[m][1][i] + acc[m][2][i] + acc[m][3][i];
                float pq = acc[m][0][i] * acc[m][0][i] + acc[m][1][i] * acc[m][1][i]
                         + acc[m][2][i] * acc[m][2][i] + acc[m][3][i] * acc[m][3][i];
                ps += __shfl_xor(ps, 1); ps += __shfl_xor(ps, 2); ps += __shfl_xor(ps, 4); ps += __shfl_xor(ps, 8);
                pq += __shfl_xor(pq, 1); pq += __shfl_xor(pq, 2); pq += __shfl_xor(pq, 4); pq += __shfl_xor(pq, 8);
                if (l15 == 0) redp[(16 * m + 4 * lg + i) * 4 + w] = make_float2(ps, pq);
            }
        }
        __syncthreads();   // all GEMM1 LDS reads + partials done
        #pragma unroll
        for (int m = 0; m < 2; ++m)
            #pragma unroll
            for (int i = 0; i < 4; ++i) {
                int r = 16 * m + 4 * lg + i;
                float4 q0 = redq[r * 2 + 0], q1 = redq[r * 2 + 1];
                float s  = q0.x + q0.z + q1.x + q1.z;
                float q  = q0.y + q0.w + q1.y + q1.w;
                float mu = s * (1.f / 256.f);
                float rstd = rsqrtf(q * (1.f / 256.f) - mu * mu + EPSV);
                #pragma unroll
                for (int t = 0; t < 4; ++t) {
                    float y = (acc[m][t][i] - mu) * rstd * sv[t] + bb[t];
                    sbuf[r * XSTR + w * 64 + t * 16 + l15] = f2bf(fmaxf(y, 0.f));
                }
            }
    }
    __syncthreads();

    // ---- GEMM2 (256x256) reading h0 from sbuf ----
    #pragma unroll
    for (int m = 0; m < 2; ++m)
        #pragma unroll
        for (int t = 0; t < 4; ++t)
            acc[m][t] = (f32x4){0.f, 0.f, 0.f, 0.f};
    for (int s = 0; s < 8; ++s) {
        bf16x8 a[2];
        #pragma unroll
        for (int m = 0; m < 2; ++m)
            a[m] = *reinterpret_cast<const bf16x8*>(&sbuf[(16 * m + l15) * XSTR + 32 * s + 8 * lg]);
        #pragma unroll
        for (int t = 0; t < 4; ++t) {
            bf16x8 b = *reinterpret_cast<const bf16x8*>(W1p + (((s * 16 + w * 4 + t) * 64 + lane) << 3));
            #pragma unroll
            for (int m = 0; m < 2; ++m)
                acc[m][t] = __builtin_amdgcn_mfma_f32_16x16x32_bf16(a[m], b, acc[m][t], 0, 0, 0);
        }
    }

    // ---- LN1 + ReLU -> h1 (overwrites h0 in sbuf after barrier) ----
    {
        float bv[4], sv[4], bb[4];
        #pragma unroll
        for (int t = 0; t < 4; ++t) {
            int n = w * 64 + t * 16 + l15;
            bv[t] = b1[n]; sv[t] = mlp_ln1_s[n]; bb[t] = mlp_ln1_b[n];
        }
        #pragma unroll
        for (int m = 0; m < 2; ++m)
            #pragma unroll
            for (int t = 0; t < 4; ++t)
                #pragma unroll
                for (int i = 0; i < 4; ++i)
                    acc[m][t][i] += bv[t];
        #pragma unroll
        for (int m = 0; m < 2; ++m) {
            #pragma unroll
            for (int i = 0; i < 4; ++i) {
                float ps = acc[m][0][i] + acc[m][1][i] + acc[m][2][i] + acc[m][3][i];
                float pq = acc[m][0][i] * acc[m][0][i] + acc[m][1][i] * acc[m][1][i]
                         + acc[m][2][i] * acc[m][2][i] + acc[m][3][i] * acc[m][3][i];
                ps += __shfl_xor(ps, 1); ps += __shfl_xor(ps, 2); ps += __shfl_xor(ps, 4); ps += __shfl_xor(ps, 8);
                pq += __shfl_xor(pq, 1); pq += __shfl_xor(pq, 2); pq += __shfl_xor(pq, 4); pq += __shfl_xor(pq, 8);
                if (l15 == 0) redp[(16 * m + 4 * lg + i) * 4 + w] = make_float2(ps, pq);
            }
        }
        __syncthreads();   // all GEMM2 LDS reads + partials done
        #pragma unroll
        for (int m = 0; m < 2; ++m)
            #pragma unroll
            for (int i = 0; i < 4; ++i) {
                int r = 16 * m + 4 * lg + i;
                float4 q0 = redq[r * 2 + 0], q1 = redq[r * 2 + 1];
                float s  = q0.x + q0.z + q1.x + q1.z;
                float q  = q0.y + q0.w + q1.y + q1.w;
                float mu = s * (1.f / 256.f);
                float rstd = rsqrtf(q * (1.f / 256.f) - mu * mu + EPSV);
                #pragma unroll
                for (int t = 0; t < 4; ++t) {
                    float y = (acc[m][t][i] - mu) * rstd * sv[t] + bb[t];
                    sbuf[r * XSTR + w * 64 + t * 16 + l15] = f2bf(fmaxf(y, 0.f));
                }
            }
    }
    __syncthreads();

    // ---- GEMM3 (32x256 @ 256x144): wave w -> rows 16*(w&1).., col-half (w>>1) ----
    // Fully-static per-branch loops (rule #20)
    {
        const int rg = w & 1;
        const int ch = w >> 1;
        const unsigned short* arow = sbuf + (16 * rg + l15) * XSTR;
        float* delta = reinterpret_cast<float*>(sbuf);
        if (ch == 0) {
            f32x4 acc3[5];
            #pragma unroll
            for (int t = 0; t < 5; ++t) acc3[t] = (f32x4){0.f, 0.f, 0.f, 0.f};
            for (int s = 0; s < 8; ++s) {
                bf16x8 a = *reinterpret_cast<const bf16x8*>(arow + 32 * s + 8 * lg);
                #pragma unroll
                for (int t = 0; t < 5; ++t) {
                    bf16x8 b = *reinterpret_cast<const bf16x8*>(W2p + (((s * 9 + t) * 64 + lane) << 3));
                    acc3[t] = __builtin_amdgcn_mfma_f32_16x16x32_bf16(a, b, acc3[t], 0, 0, 0);
                }
            }
            __syncthreads();   // all h1 LDS reads done before delta overwrite
            #pragma unroll
            for (int t = 0; t < 5; ++t)
                #pragma unroll
                for (int i = 0; i < 4; ++i)
                    delta[(16 * rg + 4 * lg + i) * DSTR + 16 * t + l15] = acc3[t][i];
        } else {
            f32x4 acc3[4];
            #pragma unroll
            for (int t = 0; t < 4; ++t) acc3[t] = (f32x4){0.f, 0.f, 0.f, 0.f};
            for (int s = 0; s < 8; ++s) {
                bf16x8 a = *reinterpret_cast<const bf16x8*>(arow + 32 * s + 8 * lg);
                #pragma unroll
                for (int t = 0; t < 4; ++t) {
                    bf16x8 b = *reinterpret_cast<const bf16x8*>(W2p + (((s * 9 + t + 5) * 64 + lane) << 3));
                    acc3[t] = __builtin_amdgcn_mfma_f32_16x16x32_bf16(a, b, acc3[t], 0, 0, 0);
                }
            }
            __syncthreads();   // matches ch==0 barrier (uniform per block)
            #pragma unroll
            for (int t = 0; t < 4; ++t)
                #pragma unroll
                for (int i = 0; i < 4; ++i)
                    delta[(16 * rg + 4 * lg + i) * DSTR + 16 * (t + 5) + l15] = acc3[t][i];
        }
    }
    __syncthreads();

    // ---- epilogue: out = mask ? base + delta + b2 : base  (non-temporal) ----
    const float* delta = reinterpret_cast<const float*>(sbuf);
    #pragma unroll
    for (int j = 0; j < 5; ++j) {
        int idx = tid + j * 256;          // 0..1151 ; 36 float4 per row, 32 rows
        if (idx < BM * 36) {
            int r = idx / 36, c4 = idx % 36;
            int grow = row0 + r;
            float4 d  = *reinterpret_cast<const float4*>(delta + r * DSTR + 4 * c4);
            float4 bb = *reinterpret_cast<const float4*>(b2 + 4 * c4);
            float4 base;
            if (c4 < 4) base = *reinterpret_cast<const float4*>(logits + (size_t)grow * 16 + 4 * c4);
            else        base = *reinterpret_cast<const float4*>(hidden + (size_t)grow * 128 + 4 * c4 - 16);
            const bool mk = lyr[r] > 0;
            f32x4 o;
            o[0] = mk ? base.x + d.x + bb.x : base.x;
            o[1] = mk ? base.y + d.y + bb.y : base.y;
            o[2] = mk ? base.z + d.z + bb.z : base.z;
            o[3] = mk ? base.w + d.w + bb.w : base.w;
            __builtin_nontemporal_store(o, reinterpret_cast<f32x4*>(out + (size_t)grow * 144 + 4 * c4));
        }
    }
}

extern "C" void kernel_launch(void* const* d_in, const int* in_sizes, int n_in,
                              void* d_out, int out_size, void* d_ws, size_t ws_size,
                              hipStream_t stream)
{
    const float* logits        = (const float*)d_in[0];
    const float* hidden        = (const float*)d_in[1];
    const float* layer_pe      = (const float*)d_in[2];
    const float* intra         = (const float*)d_in[3];
    // d_in[4] = loss: unused (LN of a scalar == its bias)
    const int*   layer         = (const int*)  d_in[5];
    const float* msg           = (const float*)d_in[6];
    const float* ln_logits_s   = (const float*)d_in[7];
    const float* ln_logits_b   = (const float*)d_in[8];
    const float* ln_hidden_s   = (const float*)d_in[9];
    const float* ln_hidden_b   = (const float*)d_in[10];
    const float* ln_layer_pe_s = (const float*)d_in[11];
    const float* ln_layer_pe_b = (const float*)d_in[12];
    const float* ln_intra_pe_s = (const float*)d_in[13];
    const float* ln_intra_pe_b = (const float*)d_in[14];
    // d_in[15] = ln_loss_s: unused
    const float* ln_loss_b     = (const float*)d_in[16];
    const float* ln_msg_s      = (const float*)d_in[17];
    const float* ln_msg_b      = (const float*)d_in[18];
    const float* W0            = (const float*)d_in[19];
    const float* b0            = (const float*)d_in[20];
    const float* mlp_ln0_s     = (const float*)d_in[21];
    const float* mlp_ln0_b     = (const float*)d_in[22];
    const float* W1            = (const float*)d_in[23];
    const float* b1            = (const float*)d_in[24];
    const float* mlp_ln1_s     = (const float*)d_in[25];
    const float* mlp_ln1_b     = (const float*)d_in[26];
    const float* W2            = (const float*)d_in[27];
    const float* b2            = (const float*)d_in[28];
    float* out = (float*)d_out;

    // workspace layout (485 KB): W0p | W1p | W2p | b0_eff
    unsigned short* W0p = (unsigned short*)d_ws;                     // 278528 B
    unsigned short* W1p = (unsigned short*)((char*)d_ws + 278528);   // 131072 B
    unsigned short* W2p = (unsigned short*)((char*)d_ws + 409600);   //  73728 B
    float*          b0e = (float*)((char*)d_ws + 483328);            //   1024 B

    // 17408 (W0p) + 8192 (W1p) + 4608 (W2p) + 8192 (b0e k-parallel) = 38400 = 150*256
    prep_kernel<<<150, 256, 0, stream>>>(W0, b0, ln_loss_b, W1, W2,
        ln_logits_s, ln_hidden_s, ln_msg_s, ln_layer_pe_s, ln_intra_pe_s,
        ln_logits_b, ln_hidden_b, ln_msg_b, ln_layer_pe_b, ln_intra_pe_b,
        W0p, W1p, W2p, b0e);

    const int N = in_sizes[5];               // 200000, divisible by BM=32
    node_update_kernel<<<N / BM, 256, 0, stream>>>(
        logits, hidden, layer_pe, intra, layer, msg,
        W0p, b0e, mlp_ln0_s, mlp_ln0_b,
        W1p, b1, mlp_ln1_s, mlp_ln1_b,
        W2p, b2, out);
}